// Round 9
// baseline (139.870 us; speedup 1.0000x reference)
//
#include <hip/hip_runtime.h>

#define NN 1000
#define HEADS_ 4
#define DM 128
#define EE 64000
#define NTOT 4000
#define ETOT 68000
#define CAP 48     // bucket holds ALL edges per dst: deg ~ Poisson(16)+1, P(>=48) ~ 1e-11
#define EB 34      // edge-builder blocks appended to the h-GEMM dispatch

// ---------------------------------------------------------------------------
// 64x64 GEMM tile, K=64: C = A @ Wt^T.  k-group swizzle g = q ^ ((r>>2)&15).
// acc[4][4] only across the staged loop -- proven spill-free (R2/R5, 60 VGPR).
// SCORE: fused GAT score epilogue (rows < 1000 only).
// ---------------------------------------------------------------------------
template <int KK, int SCORE>
__device__ void gemm64(int mi, int ni,
                       const float* __restrict__ A, const float* __restrict__ Wt,
                       float* __restrict__ C, int N,
                       const float* __restrict__ att,
                       float* __restrict__ ssrc, float* __restrict__ sdst) {
  __shared__ float As[64 * 64];
  __shared__ float Bs[64 * 64];
  int tid = threadIdx.x;
  int m0 = mi * 64, n0 = ni * 64;
  int tx = tid & 15, ty = tid >> 4;
  const float4* A4 = (const float4*)A;
  const float4* W4 = (const float4*)Wt;
  float acc[4][4] = {};

  for (int c = 0; c < KK / 64; ++c) {
    __syncthreads();
    {
      int q = tid & 15, r0 = tid >> 4;
#pragma unroll
      for (int p = 0; p < 4; ++p) {  // A: 64 rows
        int r = r0 + p * 16;
        float4 v = A4[(size_t)(m0 + r) * (KK / 4) + c * 16 + q];
        *(float4*)&As[r * 64 + ((q ^ ((r >> 2) & 15)) << 2)] = v;
      }
#pragma unroll
      for (int p = 0; p < 4; ++p) {  // B: 64 rows
        int r = r0 + p * 16;
        float4 v = W4[(size_t)(n0 + r) * (KK / 4) + c * 16 + q];
        *(float4*)&Bs[r * 64 + ((q ^ ((r >> 2) & 15)) << 2)] = v;
      }
    }
    __syncthreads();
#pragma unroll 4
    for (int q = 0; q < 16; ++q) {
      float4 a[4], b[4];
      int sa = (q ^ ty) << 2;
      int sb = (q ^ tx) << 2;
#pragma unroll
      for (int i = 0; i < 4; ++i)
        a[i] = *(const float4*)&As[(ty * 4 + i) * 64 + sa];
#pragma unroll
      for (int j = 0; j < 4; ++j)
        b[j] = *(const float4*)&Bs[(tx * 4 + j) * 64 + sb];
#pragma unroll
      for (int i = 0; i < 4; ++i)
#pragma unroll
        for (int j = 0; j < 4; ++j)
          acc[i][j] += a[i].x * b[j].x + a[i].y * b[j].y
                     + a[i].z * b[j].z + a[i].w * b[j].w;
    }
  }

  int nc = n0 + tx * 4;
#pragma unroll
  for (int i = 0; i < 4; ++i) {
    int m = m0 + ty * 4 + i;
    *(float4*)&C[(size_t)m * N + nc] =
        make_float4(acc[i][0], acc[i][1], acc[i][2], acc[i][3]);
  }

  if (SCORE && m0 < NN) {  // uniform per block
    int hsel = tx >> 3;
    int h = ni * 2 + hsel;
    int kb = (tx & 7) * 4;
    float a0[4], a1[4];
#pragma unroll
    for (int j = 0; j < 4; ++j) {
      a0[j] = att[h * 64 + kb + j];
      a1[j] = att[h * 64 + 32 + kb + j];
    }
#pragma unroll
    for (int i = 0; i < 4; ++i) {
      int m = m0 + ty * 4 + i;
      float p0 = 0.f, p1 = 0.f;
#pragma unroll
      for (int j = 0; j < 4; ++j) {
        float g = acc[i][j];
        float lr = g > 0.f ? g : 0.2f * g;
        p0 += a0[j] * lr;
        p1 += a1[j] * lr;
      }
      p0 += __shfl_xor(p0, 1, 16); p1 += __shfl_xor(p1, 1, 16);
      p0 += __shfl_xor(p0, 2, 16); p1 += __shfl_xor(p1, 2, 16);
      p0 += __shfl_xor(p0, 4, 16); p1 += __shfl_xor(p1, 4, 16);
      if ((tx & 7) == 0 && m < NN) {
        ssrc[m * HEADS_ + h] = p0;
        sdst[m * HEADS_ + h] = p1;
      }
    }
  }
}

// -------- K1: blocks 0..499 = h-GEMM (250 m-tiles x 2 n-tiles) + score
//              blocks 500..499+EB = bucket build    (R5 proven)
__global__ __launch_bounds__(256) void k1_kernel(const float* __restrict__ x,
                                                 const float* __restrict__ W,
                                                 const float* __restrict__ att,
                                                 float* __restrict__ hbuf,
                                                 float* __restrict__ ssrc,
                                                 float* __restrict__ sdst,
                                                 const int* __restrict__ ei,
                                                 int* __restrict__ cnt,
                                                 int* __restrict__ elist) {
  int bid = blockIdx.x;
  if (bid < 500) {
    gemm64<64, 1>(bid >> 1, bid & 1, x, W, hbuf, 128, att, ssrc, sdst);
  } else {
    for (int e = (bid - 500) * 256 + threadIdx.x; e < ETOT; e += EB * 256) {
      int s, d;
      if (e < EE) { s = ei[e]; d = ei[EE + e]; }
      else { s = d = e - EE; }  // self loops
      int pos = atomicAdd(&cnt[d], 1);
      if (pos < CAP) elist[d * CAP + pos] = s;
    }
  }
}

// ---------------------------------------------------------------------------
// K2 (mega2): gather(8 nodes -> LDS As) + qkv GEMM + REGISTER MHA + out_proj.
// 500 blocks x 256 threads, 49,664 B static LDS -> 2-3 blocks/CU (vs R8's
// 1 blk/CU @ 133 KB): barrier stalls in one block overlap another's compute.
// Key change vs R8: after phase B, thread (tx,ty) holds q/k/v for node ty,
// all 4 views, cols tx*4..+3 in acc[3][4][4] -- the v3/R4-verified register
// attention layout (head = tx>>3 spans lanes 8h..8h+8; reduce shfl_xor 1/2/4).
// The 97 KB qk buffer, its 3 barriers, and ~48 LDS ops/thread are deleted.
// LDS: As[32][132] (4224 f, pad: a-reads broadcast-free)
//      rg2[8192 f] overlays: A{exs[8][48][4],srcs[8][48]} -> B{Bs[128][64]}
//                            -> D{Bs2[128][64]}
//      aoS[2][32][64] (4096 f) overlays As (dead after B).
// ---------------------------------------------------------------------------
__global__ __launch_bounds__(256) void mega2_kernel(const int* __restrict__ cnt,
                                                    const int* __restrict__ elist,
                                                    const float* __restrict__ ssrc,
                                                    const float* __restrict__ sdst,
                                                    const float* __restrict__ hbuf,
                                                    const float* __restrict__ inw,
                                                    const float* __restrict__ inb,
                                                    const float* __restrict__ outw,
                                                    const float* __restrict__ outb,
                                                    const float* __restrict__ bias,
                                                    float* __restrict__ out) {
  __shared__ float smem[12416];          // 49,664 B
  float* As    = smem;                   // [32][132]
  float* rg2   = smem + 4224;            // 8192-float overlay region
  float* exsF  = rg2;                    // [8][48][4]
  int*   srcsI = (int*)(rg2 + 1536);     // [8][48]
  float* Bs    = rg2;                    // [128][64] (phase B)
  float* Bs2   = rg2;                    // [128][64] (phase D)
  float* aoS   = smem;                   // [2][32][64] (overlay on As)

  int tid = threadIdx.x;
  int g0n = blockIdx.x * 8;              // first node of tile

  // ---- phase A1: stage edges + exp(score per head): 32 threads/node ----
  {
    int ln = tid >> 5, t32 = tid & 31;
    int d = g0n + ln;
    int m = cnt[d]; if (m > CAP) m = CAP;
    for (int base = 0; base < m; base += 8) {
      int i = base + (t32 >> 2);
      if (i < m) {
        int s = elist[d * CAP + i];
        if ((t32 & 3) == 0) srcsI[ln * CAP + i] = s;
        float sc = ssrc[s * HEADS_ + (t32 & 3)] + sdst[d * HEADS_ + (t32 & 3)];
        exsF[ln * 192 + i * 4 + (t32 & 3)] = __expf(sc);  // shift-invariant
      }
    }
  }
  __syncthreads();

  // ---- phase A2: gather-aggregate h rows into As (R5-proven math) ----
  {
    int r = tid >> 3, g = tid & 7;       // row in [0,32), f4-group in [0,8)
    int ln = r >> 2, v = r & 3;
    int d = g0n + ln, b = d / NN;
    int m = cnt[d]; if (m > CAP) m = CAP;
    const float* hbase = hbuf + ((size_t)(b * 4 + v) * NN) * DM + g * 4;
    float4 a0 = make_float4(0.f, 0.f, 0.f, 0.f), a1 = a0, a2 = a0, a3 = a0;
    float4 den = make_float4(1e-16f, 1e-16f, 1e-16f, 1e-16f);
    for (int i = 0; i < m; ++i) {
      float4 ex = *(const float4*)&exsF[ln * 192 + i * 4];
      unsigned sl = (unsigned)(srcsI[ln * CAP + i] - b * NN);
      unsigned sc = sl < NN ? sl : 0u;   // clamped always-valid addr
      const float* hrow = hbase + (size_t)sc * DM;
      float4 h0 = *(const float4*)(hrow);        // head 0 cols g*4..
      float4 h1 = *(const float4*)(hrow + 32);   // head 1
      float4 h2 = *(const float4*)(hrow + 64);   // head 2
      float4 h3 = *(const float4*)(hrow + 96);   // head 3
      den.x += ex.x; den.y += ex.y; den.z += ex.z; den.w += ex.w;
      float w0 = sl < NN ? ex.x : 0.f, w1 = sl < NN ? ex.y : 0.f;
      float w2 = sl < NN ? ex.z : 0.f, w3 = sl < NN ? ex.w : 0.f;
      a0.x += w0 * h0.x; a0.y += w0 * h0.y; a0.z += w0 * h0.z; a0.w += w0 * h0.w;
      a1.x += w1 * h1.x; a1.y += w1 * h1.y; a1.z += w1 * h1.z; a1.w += w1 * h1.w;
      a2.x += w2 * h2.x; a2.y += w2 * h2.y; a2.z += w2 * h2.z; a2.w += w2 * h2.w;
      a3.x += w3 * h3.x; a3.y += w3 * h3.y; a3.z += w3 * h3.z; a3.w += w3 * h3.w;
    }
    float i0 = 1.f / den.x, i1 = 1.f / den.y, i2 = 1.f / den.z, i3 = 1.f / den.w;
    *(float4*)&As[r * 132 +       g * 4] = make_float4(a0.x * i0, a0.y * i0, a0.z * i0, a0.w * i0);
    *(float4*)&As[r * 132 +  32 + g * 4] = make_float4(a1.x * i1, a1.y * i1, a1.z * i1, a1.w * i1);
    *(float4*)&As[r * 132 +  64 + g * 4] = make_float4(a2.x * i2, a2.y * i2, a2.z * i2, a2.w * i2);
    *(float4*)&As[r * 132 +  96 + g * 4] = make_float4(a3.x * i3, a3.y * i3, a3.z * i3, a3.w * i3);
  }

  // ---- phase B: qkv GEMM (R8 structure; 32 rows, acc[3][4][4]) ----
  int tx = tid & 31, ty = tid >> 5;      // cols tx*4 in [0,128), node ty
  float acc[3][4][4] = {};
  {
    const float4* W4 = (const float4*)inw;   // [384][32]
#pragma unroll
    for (int c = 0; c < 2; ++c) {
#pragma unroll
      for (int ni = 0; ni < 3; ++ni) {
        __syncthreads();
        {
          int q = tid & 15, r0 = tid >> 4;   // r0 in [0,16)
#pragma unroll
          for (int p = 0; p < 8; ++p) {      // Bs: 128 weight rows
            int r = r0 + p * 16;
            float4 v = W4[(size_t)(ni * 128 + r) * 32 + c * 16 + q];
            *(float4*)&Bs[r * 64 + ((q ^ ((r >> 2) & 15)) << 2)] = v;
          }
        }
        __syncthreads();
#pragma unroll 4
        for (int q = 0; q < 16; ++q) {
          float4 a[4], b[4];
          int sb = (q ^ (tx & 15)) << 2;
#pragma unroll
          for (int i = 0; i < 4; ++i)
            a[i] = *(const float4*)&As[(ty * 4 + i) * 132 + c * 64 + q * 4];
#pragma unroll
          for (int j = 0; j < 4; ++j)
            b[j] = *(const float4*)&Bs[(tx * 4 + j) * 64 + sb];
#pragma unroll
          for (int i = 0; i < 4; ++i)
#pragma unroll
            for (int j = 0; j < 4; ++j)
              acc[ni][i][j] += a[i].x * b[j].x + a[i].y * b[j].y
                             + a[i].z * b[j].z + a[i].w * b[j].w;
        }
      }
    }
  }

  // ---- phase C: +inb, then attention ENTIRELY in registers ----
  // acc[p][v][j] = {q,k,v}[node ty][view v][col tx*4+j]; head = tx>>3.
#pragma unroll
  for (int ni = 0; ni < 3; ++ni) {
    float4 ib = *(const float4*)&inb[ni * 128 + tx * 4];
#pragma unroll
    for (int i = 0; i < 4; ++i) {
      acc[ni][i][0] += ib.x; acc[ni][i][1] += ib.y;
      acc[ni][i][2] += ib.z; acc[ni][i][3] += ib.w;
    }
  }
  float S[4][4];
#pragma unroll
  for (int vq = 0; vq < 4; ++vq)
#pragma unroll
    for (int vk = 0; vk < 4; ++vk)
      S[vq][vk] = acc[0][vq][0] * acc[1][vk][0] + acc[0][vq][1] * acc[1][vk][1]
                + acc[0][vq][2] * acc[1][vk][2] + acc[0][vq][3] * acc[1][vk][3];
  // reduce over the head's 8 tx-lanes (lane = (ty&1)*32 + tx; xor 1/2/4
  // flips tx bits 0-2 only -> stays within same ty and same head)
#pragma unroll
  for (int vq = 0; vq < 4; ++vq)
#pragma unroll
    for (int vk = 0; vk < 4; ++vk) {
      float s = S[vq][vk];
      s += __shfl_xor(s, 1);
      s += __shfl_xor(s, 2);
      s += __shfl_xor(s, 4);
      S[vq][vk] = s * 0.17677669529663687f;  // 1/sqrt(32)
    }
#pragma unroll
  for (int vq = 0; vq < 4; ++vq) {  // softmax over vk (redundant x8, consistent)
    float mx = fmaxf(fmaxf(S[vq][0], S[vq][1]), fmaxf(S[vq][2], S[vq][3]));
    float e0 = __expf(S[vq][0] - mx), e1 = __expf(S[vq][1] - mx);
    float e2 = __expf(S[vq][2] - mx), e3 = __expf(S[vq][3] - mx);
    float inv = 1.f / (e0 + e1 + e2 + e3);
    S[vq][0] = e0 * inv; S[vq][1] = e1 * inv; S[vq][2] = e2 * inv; S[vq][3] = e3 * inv;
  }
  float4 ao_r[4];
#pragma unroll
  for (int vq = 0; vq < 4; ++vq) {
    ao_r[vq] = make_float4(
        S[vq][0] * acc[2][0][0] + S[vq][1] * acc[2][1][0] + S[vq][2] * acc[2][2][0] + S[vq][3] * acc[2][3][0],
        S[vq][0] * acc[2][0][1] + S[vq][1] * acc[2][1][1] + S[vq][2] * acc[2][2][1] + S[vq][3] * acc[2][3][1],
        S[vq][0] * acc[2][0][2] + S[vq][1] * acc[2][1][2] + S[vq][2] * acc[2][2][2] + S[vq][3] * acc[2][3][2],
        S[vq][0] * acc[2][0][3] + S[vq][1] * acc[2][1][3] + S[vq][2] * acc[2][2][3] + S[vq][3] * acc[2][3][3]);
  }
  __syncthreads();  // all As/Bs reads (phase B) complete before overlays
  {
    // write aoS[2 chunk][32 row][64] swizzled for phase D reads:
    // row r = ty*4+vq (key r>>2 == ty), col-group g = tx&15, chunk = tx>>4
    int cc = tx >> 4, g = tx & 15;
#pragma unroll
    for (int vq = 0; vq < 4; ++vq)
      *(float4*)&aoS[cc * 2048 + (ty * 4 + vq) * 64 + ((g ^ ty) << 2)] = ao_r[vq];
  }

  // ---- phase D: out_proj 32x128, K=128 (2 chunks via Bs2); remap write ----
  float oc[4][4] = {};
  const float4* O4 = (const float4*)outw;  // [128][32]
#pragma unroll
  for (int c = 0; c < 2; ++c) {
    {
      int q = tid & 15, r0 = tid >> 4;
#pragma unroll
      for (int p = 0; p < 8; ++p) {       // Bs2: 128 outw rows
        int r = r0 + p * 16;
        float4 v = O4[(size_t)r * 32 + c * 16 + q];
        *(float4*)&Bs2[r * 64 + ((q ^ ((r >> 2) & 15)) << 2)] = v;
      }
    }
    __syncthreads();   // (first one also publishes aoS)
#pragma unroll 4
    for (int q = 0; q < 16; ++q) {
      float4 a[4], bq[4];
      int sa = (q ^ ty) << 2;
      int sb = (q ^ (tx & 15)) << 2;
#pragma unroll
      for (int i = 0; i < 4; ++i)
        a[i] = *(const float4*)&aoS[c * 2048 + (ty * 4 + i) * 64 + sa];
#pragma unroll
      for (int j = 0; j < 4; ++j)
        bq[j] = *(const float4*)&Bs2[(tx * 4 + j) * 64 + sb];
#pragma unroll
      for (int i = 0; i < 4; ++i)
#pragma unroll
        for (int j = 0; j < 4; ++j)
          oc[i][j] += a[i].x * bq[j].x + a[i].y * bq[j].y
                    + a[i].z * bq[j].z + a[i].w * bq[j].w;
    }
    __syncthreads();
  }

  {  // epilogue: +outb +bias, remap row (node,v) -> (b*4+v)*NN + n
    int nc = tx * 4;
    float4 ob = make_float4(outb[nc] + bias[nc], outb[nc + 1] + bias[nc + 1],
                            outb[nc + 2] + bias[nc + 2], outb[nc + 3] + bias[nc + 3]);
#pragma unroll
    for (int i = 0; i < 4; ++i) {
      int r = ty * 4 + i;
      int node = g0n + (r >> 2), vv = r & 3;
      int bg = node / NN, n = node - bg * NN;
      int om = (bg * 4 + vv) * NN + n;
      *(float4*)&out[(size_t)om * DM + nc] =
          make_float4(oc[i][0] + ob.x, oc[i][1] + ob.y,
                      oc[i][2] + ob.z, oc[i][3] + ob.w);
    }
  }
}

extern "C" void kernel_launch(void* const* d_in, const int* in_sizes, int n_in,
                              void* d_out, int out_size, void* d_ws, size_t ws_size,
                              hipStream_t stream) {
  const float* x    = (const float*)d_in[0];
  const float* W    = (const float*)d_in[1];
  const float* att  = (const float*)d_in[2];
  const float* inw  = (const float*)d_in[3];
  const float* inb  = (const float*)d_in[4];
  const float* outw = (const float*)d_in[5];
  const float* outb = (const float*)d_in[6];
  const float* bias = (const float*)d_in[7];
  const int*   ei   = (const int*)d_in[8];
  float* out = (float*)d_out;

  float* ws = (float*)d_ws;
  float* hbuf  = ws;                       // 2,048,000  (b,v,n)-major h
  float* ssrc  = ws + 12500000;            // 16,000 } contiguous:
  float* sdst  = ssrc + 16000;             // 16,000 } one 144 KB memset
  int*   cnt   = (int*)(sdst + 16000);     //  4,000 }
  int*   elist = cnt + 4000;               // 192,000 (4000 x CAP)

  // zero ssrc/sdst (rows >=1000 must stay zero) + cnt
  hipMemsetAsync(ssrc, 0, 36000 * sizeof(float), stream);

  k1_kernel<<<500 + EB, 256, 0, stream>>>(x, W, att, hbuf, ssrc, sdst, ei, cnt, elist);
  mega2_kernel<<<NTOT / 8, 256, 0, stream>>>(cnt, elist, ssrc, sdst, hbuf,
                                             inw, inb, outw, outb, bias, out);
}